// Round 3
// baseline (301.412 us; speedup 1.0000x reference)
//
#include <hip/hip_runtime.h>

#define TPB     128
#define LSEQ    1024          // L
#define NCOL    1022          // n = L-2
#define NROW    1021          // rows of the cumprod
#define CBLK    4             // column blocks per (b,d): 4*128 slots >= 511
#define NCHUNK  4             // row chunks
#define RCHUNK  256           // rows per chunk (last chunk: 253)

typedef float v2f __attribute__((ext_vector_type(2)));

__device__ __forceinline__ float clamp01(float x) {
    return fminf(fmaxf(x, 0.0f), 1.0f);          // v_med3_f32
}
// b^m by binary exponentiation (b in [0,1], m >= 0). Underflow-safe (0*0=0).
__device__ __forceinline__ float powi(float b, int m) {
    float r = 1.0f;
    while (m) { if (m & 1) r *= b; b *= b; m >>= 1; }
    return r;
}

// Thread owns columns (j0, j0+1) of one (b,d) matrix, rows [r0, r1).
// p(r,j) = clamp01((v - s[j])*10 + 1), v = s[j-1-r] (0 if index < 0).
// Row regions: r < j0 : real LDS reads (vhi(r+1)==vlo(r) reuse)
//              r == j0: vlo = 0, vhi = s[0]
//              r > j0 : v = 0 -> p constant per column
__global__ __launch_bounds__(TPB) void gate_kernel(
    const float* __restrict__ score,
    const int*   __restrict__ score_idx,
    float*       __restrict__ out)
{
    __shared__ float s[NCOL];

    const int bid = blockIdx.x;
    const int ch  = bid & (NCHUNK - 1);          // row chunk
    const int cb  = (bid >> 2) & (CBLK - 1);     // column block
    const int bd  = bid >> 4;                    // b*2 + d
    const int d   = bd & 1;
    const int b   = bd >> 1;
    const int tid = threadIdx.x;

    const int* idxRow = score_idx + b * LSEQ + 1;   // docs[b][1:]
    for (int i = tid; i < NCOL; i += TPB) {
        int src = (d == 0) ? i : (NCOL - 1 - i);
        s[i] = score[idxRow[src]];
    }
    __syncthreads();

    const int slot = cb * TPB + tid;
    if (slot >= NCOL / 2) return;                // 511 valid slots
    const int j0 = slot * 2;

    const float sj0 = s[j0];
    const float sj1 = s[j0 + 1];
    const float c0  = 1.0f - 10.0f * sj0;
    const float c1  = 1.0f - 10.0f * sj1;
    const float pc0 = clamp01(c0);               // p when v = 0
    const float pc1 = clamp01(c1);

    const int r0 = ch * RCHUNK;
    const int r1 = min(r0 + RCHUNK, NROW);

    float a0 = 1.0f, a1 = 1.0f;
    float vhi = sj0;
    int   k   = j0 - 1;                          // next fresh read index

#define STEP(VLO)                                              \
    {   float _v = (VLO);                                      \
        float _p0 = clamp01(__builtin_fmaf(_v,  10.0f, c0));   \
        float _p1 = clamp01(__builtin_fmaf(vhi, 10.0f, c1));   \
        a0 *= _p0; a1 *= _p1; vhi = _v; }

    // ---------------- prefix: rows [0, r0), no stores ----------------
    {
        const int nread = min(j0, r0);           // read-region rows consumed here
        int t = 0;
        for (; t + 4 <= nread; t += 4) {
            float x3 = s[k]; float x2 = s[k-1]; float x1 = s[k-2]; float x0 = s[k-3];
            k -= 4;
            STEP(x3); STEP(x2); STEP(x1); STEP(x0);
        }
        for (; t < nread; ++t) { float x = s[k]; --k; STEP(x); }

        if (r0 > j0) {                           // boundary row j0 was before r0
            float _p1 = clamp01(__builtin_fmaf(vhi, 10.0f, c1));
            a0 *= pc0; a1 *= _p1; vhi = 0.0f;
            int m = r0 - j0 - 1;                 // const rows inside prefix
            a0 *= powi(pc0, m);
            a1 *= powi(pc1, m);
        }
    }

    // ---------------- store loop: rows [r0, r1) ----------------
    float* outp = out + (size_t)bd * NROW * NCOL + (size_t)r0 * NCOL + j0;

#define EMIT  { v2f w; w.x = a0; w.y = a1;                      \
                __builtin_nontemporal_store(w, (v2f*)outp);     \
                outp += NCOL; }

    int r = r0;
    const int nrm = min(j0, r1);                 // end of read-region stores
    for (; r + 4 <= nrm; r += 4) {
        float x3 = s[k]; float x2 = s[k-1]; float x1 = s[k-2]; float x0 = s[k-3];
        k -= 4;
        STEP(x3); EMIT; STEP(x2); EMIT; STEP(x1); EMIT; STEP(x0); EMIT;
    }
    for (; r < nrm; ++r) { float x = s[k]; --k; STEP(x); EMIT; }

    if (r < r1 && r == j0) {                     // boundary row
        float _p1 = clamp01(__builtin_fmaf(vhi, 10.0f, c1));
        a0 *= pc0; a1 *= _p1; vhi = 0.0f;
        EMIT; ++r;
    }
    for (; r + 4 <= r1; r += 4) {                // constant region
        a0 *= pc0; a1 *= pc1; EMIT;
        a0 *= pc0; a1 *= pc1; EMIT;
        a0 *= pc0; a1 *= pc1; EMIT;
        a0 *= pc0; a1 *= pc1; EMIT;
    }
    for (; r < r1; ++r) { a0 *= pc0; a1 *= pc1; EMIT; }

#undef STEP
#undef EMIT
}

extern "C" void kernel_launch(void* const* d_in, const int* in_sizes, int n_in,
                              void* d_out, int out_size, void* d_ws, size_t ws_size,
                              hipStream_t stream)
{
    const float* score = (const float*)d_in[0];
    const int*   sidx  = (const int*)d_in[1];
    float*       out   = (float*)d_out;

    const int B = in_sizes[0] / LSEQ;            // 32
    dim3 grid(B * 2 * CBLK * NCHUNK), block(TPB);
    gate_kernel<<<grid, block, 0, stream>>>(score, sidx, out);
}

// Round 4
// 50.869 us; speedup vs baseline: 5.9253x; 5.9253x over previous
//
#include <hip/hip_runtime.h>

#define TPB   128
#define LSEQ  1024            // L
#define NCOL  1022            // n = L-2 (columns)
#define NROW  1021            // cumprod rows
#define NPAD  1021            // leading zeros: index j-1-r+NPAD never < 0
#define SLDS  (NPAD + NCOL)   // 2043 floats = 8172 B LDS

// One thread owns ONE column j of one (batch, dir) matrix and walks the
// serial cumprod down all 1021 rows (uniform trip count, no divergence).
// p(r,j) = clamp01((v - s[j])*10 + 1), v = s[j-1-r] (0 if index < 0).
// The LDS array is front-padded with 1021 zeros so the v=0 region needs no
// clamp/select, and batch-8 ds_reads amortize the ~120cy LDS latency.
__global__ __launch_bounds__(TPB) void gate_kernel(
    const float* __restrict__ score,
    const int*   __restrict__ score_idx,
    float*       __restrict__ out)
{
    __shared__ float sp[SLDS];

    const int bid = blockIdx.x;
    const int cb  = bid & 7;            // 8 column blocks x 128 threads
    const int bd  = bid >> 3;           // b*2 + d
    const int d   = bd & 1;
    const int b   = bd >> 1;
    const int tid = threadIdx.x;

    for (int i = tid; i < NPAD; i += TPB) sp[i] = 0.0f;
    const int* idxRow = score_idx + b * LSEQ + 1;      // docs[b][1:]
    for (int i = tid; i < NCOL; i += TPB) {
        int src = (d == 0) ? i : (NCOL - 1 - i);
        sp[NPAD + i] = score[idxRow[src]];
    }
    __syncthreads();

    const int j = cb * TPB + tid;
    if (j >= NCOL) return;              // 2 idle lanes in the last block

    const float c = 1.0f - 10.0f * sp[NPAD + j];
    float a = 1.0f;
    int   m = NPAD + j - 1;             // sp index of v at row r (descending)
    float* outp = out + (size_t)bd * NROW * NCOL + j;

#define ROW(X)                                                        \
    {   float p = fminf(fmaxf(__builtin_fmaf((X), 10.0f, c), 0.0f), 1.0f); \
        a *= p; *outp = a; outp += NCOL; }

    // 127 full batches of 8 rows
    for (int bt = 0; bt < NROW / 8; ++bt) {
        float x0 = sp[m    ], x1 = sp[m - 1], x2 = sp[m - 2], x3 = sp[m - 3];
        float x4 = sp[m - 4], x5 = sp[m - 5], x6 = sp[m - 6], x7 = sp[m - 7];
        m -= 8;
        ROW(x0); ROW(x1); ROW(x2); ROW(x3);
        ROW(x4); ROW(x5); ROW(x6); ROW(x7);
    }
    // tail: 5 rows
    {
        float x0 = sp[m], x1 = sp[m - 1], x2 = sp[m - 2], x3 = sp[m - 3];
        float x4 = sp[m - 4];
        ROW(x0); ROW(x1); ROW(x2); ROW(x3); ROW(x4);
    }
#undef ROW
}

extern "C" void kernel_launch(void* const* d_in, const int* in_sizes, int n_in,
                              void* d_out, int out_size, void* d_ws, size_t ws_size,
                              hipStream_t stream)
{
    const float* score = (const float*)d_in[0];
    const int*   sidx  = (const int*)d_in[1];
    float*       out   = (float*)d_out;

    const int B = in_sizes[0] / LSEQ;   // 32
    dim3 grid(B * 2 * 8), block(TPB);   // 512 blocks x 128 threads
    gate_kernel<<<grid, block, 0, stream>>>(score, sidx, out);
}